// Round 7
// baseline (175.602 us; speedup 1.0000x reference)
//
#include <hip/hip_runtime.h>
#include <cstdint>
#include <cstddef>

#define NB 8
#define NS 2048
#define ND 768
#define NSP 512
#define MAXW 30
#define NH 100
#define LDP 104        // P row stride in floats (26 float4)
#define NKS 24         // 768 / 32
#define NCF 7          // 101 used cols = 7 frags of 16
#define NBLK 256
#define NTHR 512
#define NWAVES (NBLK * NTHR / 64)   // 2048

typedef __attribute__((ext_vector_type(8))) short short8;
typedef __attribute__((ext_vector_type(4))) float floatx4;

union U4S8 { uint4 v; short8 s8; unsigned u[4]; unsigned short us[8]; };

__device__ inline unsigned short f2bf(float f) {
    unsigned u = __float_as_uint(f);
    return (unsigned short)((u + 0x7fffu + ((u >> 16) & 1u)) >> 16);
}

// truncate-split of a float pair into packed bf16x2 hi / lo-residual.
__device__ inline void split2(float x0, float x1, unsigned& hi, unsigned& lo) {
    unsigned u0 = __float_as_uint(x0), u1 = __float_as_uint(x1);
    unsigned h0 = u0 & 0xFFFF0000u, h1 = u1 & 0xFFFF0000u;
    hi = (u0 >> 16) | h1;
    float r0 = x0 - __uint_as_float(h0);
    float r1 = x1 - __uint_as_float(h1);
    lo = (__float_as_uint(r0) >> 16) | (__float_as_uint(r1) & 0xFFFF0000u);
}

// Manual grid barrier: 256 blocks <= 256 CUs x >=1 co-resident block each, so
// all blocks are always resident -> spin cannot deadlock. Agent-scope atomics
// + __threadfence for cross-XCD data visibility.
__device__ inline void grid_barrier(int* cnt, int* flag) {
    __syncthreads();
    if (threadIdx.x == 0) {
        __threadfence();   // prior writes visible at agent scope
        int old = __hip_atomic_fetch_add(cnt, 1, __ATOMIC_ACQ_REL, __HIP_MEMORY_SCOPE_AGENT);
        if (old == NBLK - 1) {
            __hip_atomic_store(flag, 1, __ATOMIC_RELEASE, __HIP_MEMORY_SCOPE_AGENT);
        } else {
            while (__hip_atomic_load(flag, __ATOMIC_ACQUIRE, __HIP_MEMORY_SCOPE_AGENT) == 0)
                __builtin_amdgcn_s_sleep(4);
        }
        __threadfence();
    }
    __syncthreads();
}

template<int NF>
__device__ inline void proj_job(int tile, int cf0, int lane, int q, int r,
                                const float* __restrict__ seq,
                                const uint4* __restrict__ Bfrag,
                                float* __restrict__ P, float* __restrict__ Lg)
{
    const int row0 = tile * 16;
    const float4* a4 = (const float4*)(seq + (size_t)(row0 + r) * ND) + q * 2;
    const uint4* bp = Bfrag + (size_t)cf0 * 64 + lane;   // frag(ks,cf) at (ks*7+cf)*64

    floatx4 acc[NF];
#pragma unroll
    for (int c = 0; c < NF; ++c) acc[c] = (floatx4){0.f, 0.f, 0.f, 0.f};

    // register pipeline: A depth-2, B depth-1 (clamped prefetch, branch-free)
    float4 A00 = a4[0], A01 = a4[1];
    float4 A10 = a4[8], A11 = a4[9];
    uint4 Bc[NF];
#pragma unroll
    for (int c = 0; c < NF; ++c) Bc[c] = bp[c * 64];

    for (int ks = 0; ks < NKS; ++ks) {
        const int pa = (ks + 2 < NKS ? ks + 2 : NKS - 1) * 8;
        const size_t pb = (size_t)(ks + 1 < NKS ? ks + 1 : NKS - 1) * (NCF * 64);
        float4 N0 = a4[pa], N1 = a4[pa + 1];
        uint4 Bn[NF];
#pragma unroll
        for (int c = 0; c < NF; ++c) Bn[c] = bp[pb + c * 64];

        U4S8 hi, lo;
        split2(A00.x, A00.y, hi.u[0], lo.u[0]);
        split2(A00.z, A00.w, hi.u[1], lo.u[1]);
        split2(A01.x, A01.y, hi.u[2], lo.u[2]);
        split2(A01.z, A01.w, hi.u[3], lo.u[3]);

#pragma unroll
        for (int c = 0; c < NF; ++c) {
            U4S8 b; b.v = Bc[c];
            acc[c] = __builtin_amdgcn_mfma_f32_16x16x32_bf16(hi.s8, b.s8, acc[c], 0, 0, 0);
            acc[c] = __builtin_amdgcn_mfma_f32_16x16x32_bf16(lo.s8, b.s8, acc[c], 0, 0, 0);
        }
        A00 = A10; A01 = A11; A10 = N0; A11 = N1;
#pragma unroll
        for (int c = 0; c < NF; ++c) Bc[c] = Bn[c];
    }

    // C/D layout: col = (cf0+c)*16 + r, row = row0 + q*4 + reg
#pragma unroll
    for (int c = 0; c < NF; ++c) {
        int col = (cf0 + c) * 16 + r;
        if (col < NH) {
#pragma unroll
            for (int reg = 0; reg < 4; ++reg)
                P[(size_t)(row0 + q * 4 + reg) * LDP + col] = acc[c][reg];
        } else if (col == NH) {
#pragma unroll
            for (int reg = 0; reg < 4; ++reg)
                Lg[row0 + q * 4 + reg] = acc[c][reg];
        }
    }
}

// Persistent fused kernel: pack B -> grid barrier -> proj -> grid barrier -> spans.
// 256 blocks x 512 threads (1 block/CU guaranteed resident).
__global__ __launch_bounds__(NTHR) void fused_kernel(
    const float* __restrict__ seq, const int* __restrict__ span_idx,
    const int* __restrict__ span_mask, const float* __restrict__ att_w,
    const float* __restrict__ ffnn_w, const float* __restrict__ ffnn_b,
    float* __restrict__ out, float* __restrict__ P,
    uint4* __restrict__ Bfrag, float* __restrict__ Lg, int* __restrict__ bar)
{
    const int wave = threadIdx.x >> 6, lane = threadIdx.x & 63;
    const int q = lane >> 4, r = lane & 15;
    const int wid = blockIdx.x * 8 + wave;     // 0..2047

    // ---- Phase 0: pack B = [ffnn_w | att_w] into MFMA B-frag order (168 jobs) ----
    if (wid < NKS * NCF) {
        int ks = wid / NCF, cf = wid - ks * NCF;
        int n = cf * 16 + r;
        U4S8 p;
#pragma unroll
        for (int j = 0; j < 8; j++) {
            int k = ks * 32 + q * 8 + j;
            float v = (n < NH) ? ffnn_w[(size_t)k * NH + n]
                               : (n == NH ? att_w[k] : 0.f);
            p.us[j] = f2bf(v);
        }
        Bfrag[(size_t)wid * 64 + lane] = p.v;
    }
    grid_barrier(bar + 0, bar + 1);

    // ---- Phase 1: proj. 2048 jobs = 1024 row-tiles x 2 col-halves; 1 job/wave ----
    {
        const int tile = wid >> 1, half = wid & 1;
        if (half == 0) proj_job<4>(tile, 0, lane, q, r, seq, Bfrag, P, Lg);
        else           proj_job<3>(tile, 4, lane, q, r, seq, Bfrag, P, Lg);
    }
    grid_barrier(bar + 2, bar + 3);

    // ---- Phase 2: spans. 4096 spans; 2 per wave ----
#pragma unroll
    for (int j = 0; j < 2; ++j) {
        const int gs = wid + j * NWAVES;
        const int b = gs / NSP;
        const int st = span_idx[2 * gs];
        int w = span_idx[2 * gs + 1] - st;
        w = max(1, min(w, MAXW));

        float lg = -1e30f;
        if (lane < w) lg = Lg[b * NS + st + lane];
        float mx = lg;
#pragma unroll
        for (int off = 32; off > 0; off >>= 1) mx = fmaxf(mx, __shfl_xor(mx, off));
        float e = (lane < w) ? __expf(lg - mx) : 0.f;
        float sum = e;
#pragma unroll
        for (int off = 32; off > 0; off >>= 1) sum += __shfl_xor(sum, off);
        float attn = e / sum;                  // 0 for lanes >= w

        int cl = min(lane, 24);
        const float4* Pb4 = (const float4*)(P + ((size_t)b * NS + st) * LDP) + cl;
        float4 acc = {0.f, 0.f, 0.f, 0.f};
#pragma unroll
        for (int i = 0; i < MAXW; ++i) {       // fixed trip; attn_i==0 for i>=w
            float a = __shfl(attn, i);
            float4 v = Pb4[i * (LDP / 4)];
            acc.x += a * v.x; acc.y += a * v.y; acc.z += a * v.z; acc.w += a * v.w;
        }

        if (lane < 25) {
            float m = (float)span_mask[gs];
            float4 bias = ((const float4*)ffnn_b)[lane];
            float4 o;
            o.x = tanhf(m * acc.x + bias.x);
            o.y = tanhf(m * acc.y + bias.y);
            o.z = tanhf(m * acc.z + bias.z);
            o.w = tanhf(m * acc.w + bias.w);
            *(float4*)(out + (size_t)gs * NH + 4 * lane) = o;
        }
    }
}

extern "C" void kernel_launch(void* const* d_in, const int* in_sizes, int n_in,
                              void* d_out, int out_size, void* d_ws, size_t ws_size,
                              hipStream_t stream) {
    const float* seq      = (const float*)d_in[0];  // [B,S,D]
    const int*   span_idx = (const int*)d_in[1];    // [B,N,2] int32 on device
    const int*   span_msk = (const int*)d_in[2];    // [B,N]
    const float* att_w    = (const float*)d_in[3];  // [D,1]
    // d_in[4] = att_b: cancels inside softmax — unused
    const float* ffnn_w   = (const float*)d_in[5];  // [D,H]
    const float* ffnn_b   = (const float*)d_in[6];  // [H]
    float* out = (float*)d_out;                     // [B,N,H]

    char* ws = (char*)d_ws;
    size_t off = 0;
    float* P     = (float*)(ws + off); off += (size_t)NB * NS * LDP * 4;        // 6.82 MB
    uint4* Bfrag = (uint4*)(ws + off); off += (size_t)NKS * NCF * 64 * 16;      // 172 KB
    float* Lg    = (float*)(ws + off); off += (size_t)NB * NS * 4;              // 64 KB
    int*   bar   = (int*)(ws + ((off + 255) & ~(size_t)255));

    // d_ws is re-poisoned to 0xAA before every launch: zero the barrier slots.
    hipMemsetAsync(bar, 0, 256, stream);

    fused_kernel<<<NBLK, NTHR, 0, stream>>>(
        seq, span_idx, span_msk, att_w, ffnn_w, ffnn_b, out, P, Bfrag, Lg, bar);
}

// Round 8
// 140.663 us; speedup vs baseline: 1.2484x; 1.2484x over previous
//
#include <hip/hip_runtime.h>
#include <cstdint>
#include <cstddef>

#define NB 8
#define NS 2048
#define ND 768
#define NSP 512
#define MAXW 30
#define NH 100
#define LDP 104        // P row stride in floats (26 float4)
#define NKS 24         // 768 / 32
#define NCF 7          // 101 used cols = 7 frags of 16

typedef __attribute__((ext_vector_type(8))) short short8;
typedef __attribute__((ext_vector_type(4))) float floatx4;

union U4S8 { uint4 v; short8 s8; unsigned u[4]; unsigned short us[8]; };

__device__ inline unsigned short f2bf(float f) {
    unsigned u = __float_as_uint(f);
    return (unsigned short)((u + 0x7fffu + ((u >> 16) & 1u)) >> 16);
}

// truncate-split of a float pair into packed bf16x2 hi / lo-residual.
__device__ inline void split2(float x0, float x1, unsigned& hi, unsigned& lo) {
    unsigned u0 = __float_as_uint(x0), u1 = __float_as_uint(x1);
    unsigned h0 = u0 & 0xFFFF0000u, h1 = u1 & 0xFFFF0000u;
    hi = (u0 >> 16) | h1;
    float r0 = x0 - __uint_as_float(h0);
    float r1 = x1 - __uint_as_float(h1);
    lo = (__float_as_uint(r0) >> 16) | (__float_as_uint(r1) & 0xFFFF0000u);
}

// Kernel 0: pack B = [ffnn_w | att_w] (768 x 101->112) into MFMA B-frag order, bf16.
// Frag (ks, cf) at (ks*7+cf)*64: lane l holds B[ks*32 + (l>>4)*8 + j][cf*16 + (l&15)].
__global__ __launch_bounds__(256) void pack_b_kernel(
    const float* __restrict__ ffnn_w, const float* __restrict__ att_w,
    uint4* __restrict__ Bfrag)
{
    int ks = blockIdx.x;
    for (int idx = threadIdx.x; idx < NCF * 64; idx += 256) {
        int cf = idx >> 6, lane = idx & 63;
        int q = lane >> 4, r = lane & 15;
        int n = cf * 16 + r;
        U4S8 p;
#pragma unroll
        for (int j = 0; j < 8; j++) {
            int k = ks * 32 + q * 8 + j;
            float v = (n < NH) ? ffnn_w[(size_t)k * NH + n]
                               : (n == NH ? att_w[k] : 0.f);
            p.us[j] = f2bf(v);
        }
        Bfrag[(size_t)(ks * NCF + cf) * 64 + lane] = p.v;
    }
}

// Kernel 1: proj. Block = 448 threads = 7 waves = ONE 16-row tile; wave w owns
// col-frag cf=w. All 7 waves read the same A rows (L1/L2 shared). 1024 blocks
// -> 7168 waves (28/CU). Chunk-2 K-loop, next chunk fully prefetched into regs.
__global__ __launch_bounds__(448, 6) void proj_kernel(
    const float* __restrict__ seq, const uint4* __restrict__ Bfrag,
    float* __restrict__ P, float* __restrict__ Lg)
{
    const int cf = threadIdx.x >> 6, lane = threadIdx.x & 63;
    const int q = lane >> 4, r = lane & 15;
    const int row0 = blockIdx.x * 16;

    const float4* a4 = (const float4*)(seq + (size_t)(row0 + r) * ND) + q * 2;
    const uint4* bp = Bfrag + (size_t)cf * 64 + lane;   // + ks*448 per k-step

    floatx4 acc = {0.f, 0.f, 0.f, 0.f};

    // chunk = 2 k-steps (64 k). Prefetch next chunk while computing current.
    float4 A0 = a4[0], A1 = a4[1], A2 = a4[8], A3 = a4[9];
    uint4  B0 = bp[0], B1 = bp[448];

    for (int c = 0; c < NKS / 2; ++c) {
        const int nc = (c + 1 < NKS / 2) ? c + 1 : c;
        const int na = nc * 16;
        const size_t nb = (size_t)nc * 2 * 448;
        float4 N0 = a4[na], N1 = a4[na + 1], N2 = a4[na + 8], N3 = a4[na + 9];
        uint4  M0 = bp[nb], M1 = bp[nb + 448];

        U4S8 hi, lo, b;
        split2(A0.x, A0.y, hi.u[0], lo.u[0]);
        split2(A0.z, A0.w, hi.u[1], lo.u[1]);
        split2(A1.x, A1.y, hi.u[2], lo.u[2]);
        split2(A1.z, A1.w, hi.u[3], lo.u[3]);
        b.v = B0;
        acc = __builtin_amdgcn_mfma_f32_16x16x32_bf16(hi.s8, b.s8, acc, 0, 0, 0);
        acc = __builtin_amdgcn_mfma_f32_16x16x32_bf16(lo.s8, b.s8, acc, 0, 0, 0);

        split2(A2.x, A2.y, hi.u[0], lo.u[0]);
        split2(A2.z, A2.w, hi.u[1], lo.u[1]);
        split2(A3.x, A3.y, hi.u[2], lo.u[2]);
        split2(A3.z, A3.w, hi.u[3], lo.u[3]);
        b.v = B1;
        acc = __builtin_amdgcn_mfma_f32_16x16x32_bf16(hi.s8, b.s8, acc, 0, 0, 0);
        acc = __builtin_amdgcn_mfma_f32_16x16x32_bf16(lo.s8, b.s8, acc, 0, 0, 0);

        A0 = N0; A1 = N1; A2 = N2; A3 = N3;
        B0 = M0; B1 = M1;
    }

    // C/D layout: col = cf*16 + r, row = row0 + q*4 + reg
    const int col = cf * 16 + r;
    if (col < NH) {
#pragma unroll
        for (int reg = 0; reg < 4; ++reg)
            P[(size_t)(row0 + q * 4 + reg) * LDP + col] = acc[reg];
    } else if (col == NH) {
#pragma unroll
        for (int reg = 0; reg < 4; ++reg)
            Lg[row0 + q * 4 + reg] = acc[reg];
    }
}

// Kernel 2: one wave per span (4096 waves, 16/CU). Softmax over Lg (att_b
// cancels), then out[n, 4l..4l+3] = tanh(mask * sum_i attn_i * P4[st+i, l] + b4[l]).
__global__ __launch_bounds__(256) void span_kernel(
    const int* __restrict__ span_idx, const int* __restrict__ span_mask,
    const float* __restrict__ P, const float* __restrict__ Lg,
    const float* __restrict__ ffnn_b, float* __restrict__ out)
{
    const int wave = threadIdx.x >> 6, lane = threadIdx.x & 63;
    const int gs = blockIdx.x * 4 + wave;          // [0, 4096)
    const int b = gs / NSP;
    const int st = span_idx[2 * gs];
    int w = span_idx[2 * gs + 1] - st;             // width in [1, MAXW]
    w = max(1, min(w, MAXW));

    float lg = -1e30f;
    if (lane < w) lg = Lg[b * NS + st + lane];
    float mx = lg;
#pragma unroll
    for (int off = 32; off > 0; off >>= 1) mx = fmaxf(mx, __shfl_xor(mx, off));
    float e = (lane < w) ? __expf(lg - mx) : 0.f;
    float sum = e;
#pragma unroll
    for (int off = 32; off > 0; off >>= 1) sum += __shfl_xor(sum, off);
    float attn = e / sum;                          // 0 for lanes >= w

    int cl = min(lane, 24);
    const float4* Pb4 = (const float4*)(P + ((size_t)b * NS + st) * LDP) + cl;
    float4 acc = {0.f, 0.f, 0.f, 0.f};
#pragma unroll
    for (int i = 0; i < MAXW; ++i) {               // fixed trip; attn_i==0 for i>=w
        float a = __shfl(attn, i);
        float4 v = Pb4[i * (LDP / 4)];
        acc.x += a * v.x; acc.y += a * v.y; acc.z += a * v.z; acc.w += a * v.w;
    }

    if (lane < 25) {
        float m = (float)span_mask[gs];
        float4 bias = ((const float4*)ffnn_b)[lane];
        float4 o;
        o.x = tanhf(m * acc.x + bias.x);
        o.y = tanhf(m * acc.y + bias.y);
        o.z = tanhf(m * acc.z + bias.z);
        o.w = tanhf(m * acc.w + bias.w);
        *(float4*)(out + (size_t)gs * NH + 4 * lane) = o;
    }
}

extern "C" void kernel_launch(void* const* d_in, const int* in_sizes, int n_in,
                              void* d_out, int out_size, void* d_ws, size_t ws_size,
                              hipStream_t stream) {
    const float* seq      = (const float*)d_in[0];  // [B,S,D]
    const int*   span_idx = (const int*)d_in[1];    // [B,N,2] int32 on device
    const int*   span_msk = (const int*)d_in[2];    // [B,N]
    const float* att_w    = (const float*)d_in[3];  // [D,1]
    // d_in[4] = att_b: cancels inside softmax — unused
    const float* ffnn_w   = (const float*)d_in[5];  // [D,H]
    const float* ffnn_b   = (const float*)d_in[6];  // [H]
    float* out = (float*)d_out;                     // [B,N,H]

    char* ws = (char*)d_ws;
    size_t off = 0;
    float* P     = (float*)(ws + off); off += (size_t)NB * NS * LDP * 4;    // 6.82 MB
    uint4* Bfrag = (uint4*)(ws + off); off += (size_t)NKS * NCF * 64 * 16;  // 172 KB
    float* Lg    = (float*)(ws + off);                                      // 64 KB

    pack_b_kernel<<<NKS, 256, 0, stream>>>(ffnn_w, att_w, Bfrag);
    proj_kernel<<<(NB * NS) / 16, 448, 0, stream>>>(seq, Bfrag, P, Lg);
    span_kernel<<<(NB * NSP) / 4, 256, 0, stream>>>(span_idx, span_msk, P, Lg, ffnn_b, out);
}

// Round 9
// 118.474 us; speedup vs baseline: 1.4822x; 1.1873x over previous
//
#include <hip/hip_runtime.h>
#include <cstdint>
#include <cstddef>

#define NB 8
#define NS 2048
#define ND 768
#define NSP 512
#define MAXW 30
#define NH 100
#define LDP 104        // P row stride in floats (26 float4)
#define NKS 24         // 768 / 32 k-steps
#define NCF 8          // 8 col-frags of 16 (cols 0..99 = h, 100 = logit, 101..127 = 0)
#define BM 32          // rows per block tile
#define BKF 64         // k per outer iter (2 k-steps)
#define NIT 12         // 768 / 64

typedef __attribute__((ext_vector_type(8))) short short8;
typedef __attribute__((ext_vector_type(4))) float floatx4;

union U4S8 { uint4 v; short8 s8; unsigned u[4]; unsigned short us[8]; };

__device__ inline unsigned short f2bf(float f) {
    unsigned u = __float_as_uint(f);
    return (unsigned short)((u + 0x7fffu + ((u >> 16) & 1u)) >> 16);
}

// truncate-split of a float pair into packed bf16x2 hi / lo-residual.
__device__ inline void split2(float x0, float x1, unsigned& hi, unsigned& lo) {
    unsigned u0 = __float_as_uint(x0), u1 = __float_as_uint(x1);
    unsigned h0 = u0 & 0xFFFF0000u, h1 = u1 & 0xFFFF0000u;
    hi = (u0 >> 16) | h1;
    float r0 = x0 - __uint_as_float(h0);
    float r1 = x1 - __uint_as_float(h1);
    lo = (__float_as_uint(r0) >> 16) | (__float_as_uint(r1) & 0xFFFF0000u);
}

// Kernel 0: pack B = [ffnn_w | att_w | 0] (768 x 128) into MFMA B-frag order, bf16.
// Frag (ks, cf) at (ks*8+cf)*64: lane l holds B[ks*32 + (l>>4)*8 + j][cf*16 + (l&15)].
__global__ __launch_bounds__(256) void pack_b_kernel(
    const float* __restrict__ ffnn_w, const float* __restrict__ att_w,
    uint4* __restrict__ Bfrag)
{
    int ks = blockIdx.x;
    for (int idx = threadIdx.x; idx < NCF * 64; idx += 256) {
        int cf = idx >> 6, lane = idx & 63;
        int q = lane >> 4, r = lane & 15;
        int n = cf * 16 + r;
        U4S8 p;
#pragma unroll
        for (int j = 0; j < 8; j++) {
            int k = ks * 32 + q * 8 + j;
            float v = (n < NH) ? ffnn_w[(size_t)k * NH + n]
                               : (n == NH ? att_w[k] : 0.f);
            p.us[j] = f2bf(v);
        }
        Bfrag[(size_t)(ks * NCF + cf) * 64 + lane] = p.v;
    }
}

// Kernel 1: proj, m97-style. 512 blocks x 256 threads (4 waves).
// Block tile: 32 rows x 128 cols. Wave (wr,wc): rows wr*16.., col-frags wc*4..+3.
// A staged via LDS (coalesced float4 loads, padded stride 68 -> conflict-free
// ds_read_b128); B register-direct from L2; 2-barrier K-loop with global prefetch.
__global__ __launch_bounds__(256) void proj_kernel(
    const float* __restrict__ seq, const uint4* __restrict__ Bfrag,
    float* __restrict__ P, float* __restrict__ Lg)
{
    __shared__ float As[BM][BKF + 4];      // row stride 68 floats
    const int t = threadIdx.x;
    const int wave = t >> 6, lane = t & 63;
    const int q = lane >> 4, r = lane & 15;
    const int wr = wave & 1, wc = wave >> 1;
    const int cf0 = wc * 4;
    const int row0 = blockIdx.x * BM;

    floatx4 acc[4] = {{0.f,0.f,0.f,0.f},{0.f,0.f,0.f,0.f},
                      {0.f,0.f,0.f,0.f},{0.f,0.f,0.f,0.f}};

    // staging: thread t copies float4 sc of rows sr and sr+16 (fully coalesced)
    const int sr = t >> 4, sc = t & 15;
    const float4* gA0 = (const float4*)(seq + (size_t)(row0 + sr) * ND);
    const float4* gA1 = (const float4*)(seq + (size_t)(row0 + 16 + sr) * ND);
    float* w0 = &As[sr][sc * 4];
    float* w1 = &As[16 + sr][sc * 4];

    float4 s0 = gA0[sc], s1 = gA1[sc];

    const float* rdbase = &As[wr * 16 + r][q * 8];
    const uint4* bp = Bfrag + (size_t)cf0 * 64 + lane;

    for (int i = 0; i < NIT; ++i) {
        __syncthreads();                   // prev tile's reads done
        *(float4*)w0 = s0;
        *(float4*)w1 = s1;
        __syncthreads();                   // tile i ready
        const int nx = (i + 1 < NIT ? i + 1 : i) * 16 + sc;
        s0 = gA0[nx]; s1 = gA1[nx];        // prefetch tile i+1 (in flight over compute)

        // B frags for both k-steps of this tile (L2-resident)
        uint4 Bv[8];
#pragma unroll
        for (int ksl = 0; ksl < 2; ++ksl)
#pragma unroll
            for (int c = 0; c < 4; ++c)
                Bv[ksl * 4 + c] = bp[(size_t)((i * 2 + ksl) * NCF) * 64 + c * 64];

#pragma unroll
        for (int ksl = 0; ksl < 2; ++ksl) {
            float4 a0 = *(const float4*)(rdbase + ksl * 32);
            float4 a1 = *(const float4*)(rdbase + ksl * 32 + 4);
            U4S8 hi, lo;
            split2(a0.x, a0.y, hi.u[0], lo.u[0]);
            split2(a0.z, a0.w, hi.u[1], lo.u[1]);
            split2(a1.x, a1.y, hi.u[2], lo.u[2]);
            split2(a1.z, a1.w, hi.u[3], lo.u[3]);
#pragma unroll
            for (int c = 0; c < 4; ++c) {
                U4S8 b; b.v = Bv[ksl * 4 + c];
                acc[c] = __builtin_amdgcn_mfma_f32_16x16x32_bf16(hi.s8, b.s8, acc[c], 0, 0, 0);
                acc[c] = __builtin_amdgcn_mfma_f32_16x16x32_bf16(lo.s8, b.s8, acc[c], 0, 0, 0);
            }
        }
    }

    // C/D layout: col = (cf0+c)*16 + r, row = row0 + wr*16 + q*4 + reg
#pragma unroll
    for (int c = 0; c < 4; ++c) {
        const int col = (cf0 + c) * 16 + r;
        const int rowb = row0 + wr * 16 + q * 4;
        if (col < NH) {
#pragma unroll
            for (int reg = 0; reg < 4; ++reg)
                P[(size_t)(rowb + reg) * LDP + col] = acc[c][reg];
        } else if (col == NH) {
#pragma unroll
            for (int reg = 0; reg < 4; ++reg)
                Lg[rowb + reg] = acc[c][reg];
        }
    }
}

// Kernel 2: one wave per span (4096 waves). Softmax over Lg (att_b cancels),
// then out[n, 4l..4l+3] = tanh(mask * sum_i attn_i * P4[st+i, l] + b4[l]).
__global__ __launch_bounds__(256) void span_kernel(
    const int* __restrict__ span_idx, const int* __restrict__ span_mask,
    const float* __restrict__ P, const float* __restrict__ Lg,
    const float* __restrict__ ffnn_b, float* __restrict__ out)
{
    const int wave = threadIdx.x >> 6, lane = threadIdx.x & 63;
    const int gs = blockIdx.x * 4 + wave;          // [0, 4096)
    const int b = gs / NSP;
    const int st = span_idx[2 * gs];
    int w = span_idx[2 * gs + 1] - st;             // width in [1, MAXW]
    w = max(1, min(w, MAXW));

    float lg = -1e30f;
    if (lane < w) lg = Lg[b * NS + st + lane];
    float mx = lg;
#pragma unroll
    for (int off = 32; off > 0; off >>= 1) mx = fmaxf(mx, __shfl_xor(mx, off));
    float e = (lane < w) ? __expf(lg - mx) : 0.f;
    float sum = e;
#pragma unroll
    for (int off = 32; off > 0; off >>= 1) sum += __shfl_xor(sum, off);
    float attn = e / sum;                          // 0 for lanes >= w

    int cl = min(lane, 24);
    const float4* Pb4 = (const float4*)(P + ((size_t)b * NS + st) * LDP) + cl;
    float4 acc = {0.f, 0.f, 0.f, 0.f};
#pragma unroll
    for (int i = 0; i < MAXW; ++i) {               // fixed trip; attn_i==0 for i>=w
        float a = __shfl(attn, i);
        float4 v = Pb4[i * (LDP / 4)];
        acc.x += a * v.x; acc.y += a * v.y; acc.z += a * v.z; acc.w += a * v.w;
    }

    if (lane < 25) {
        float m = (float)span_mask[gs];
        float4 bias = ((const float4*)ffnn_b)[lane];
        float4 o;
        o.x = tanhf(m * acc.x + bias.x);
        o.y = tanhf(m * acc.y + bias.y);
        o.z = tanhf(m * acc.z + bias.z);
        o.w = tanhf(m * acc.w + bias.w);
        *(float4*)(out + (size_t)gs * NH + 4 * lane) = o;
    }
}

extern "C" void kernel_launch(void* const* d_in, const int* in_sizes, int n_in,
                              void* d_out, int out_size, void* d_ws, size_t ws_size,
                              hipStream_t stream) {
    const float* seq      = (const float*)d_in[0];  // [B,S,D]
    const int*   span_idx = (const int*)d_in[1];    // [B,N,2] int32 on device
    const int*   span_msk = (const int*)d_in[2];    // [B,N]
    const float* att_w    = (const float*)d_in[3];  // [D,1]
    // d_in[4] = att_b: cancels inside softmax — unused
    const float* ffnn_w   = (const float*)d_in[5];  // [D,H]
    const float* ffnn_b   = (const float*)d_in[6];  // [H]
    float* out = (float*)d_out;                     // [B,N,H]

    char* ws = (char*)d_ws;
    size_t off = 0;
    float* P     = (float*)(ws + off); off += (size_t)NB * NS * LDP * 4;    // 6.82 MB
    uint4* Bfrag = (uint4*)(ws + off); off += (size_t)NKS * NCF * 64 * 16;  // 192 KB
    float* Lg    = (float*)(ws + off);                                      // 64 KB

    pack_b_kernel<<<NKS, 256, 0, stream>>>(ffnn_w, att_w, Bfrag);
    proj_kernel<<<(NB * NS) / BM, 256, 0, stream>>>(seq, Bfrag, P, Lg);
    span_kernel<<<(NB * NSP) / 4, 256, 0, stream>>>(span_idx, span_msk, P, Lg, ffnn_b, out);
}

// Round 10
// 115.469 us; speedup vs baseline: 1.5208x; 1.0260x over previous
//
#include <hip/hip_runtime.h>
#include <cstdint>
#include <cstddef>

#define NB 8
#define NS 2048
#define ND 768
#define NSP 512
#define MAXW 30
#define NH 100
#define LDP 104        // P row stride in floats (26 float4)
#define NKS 24         // 768 / 32 k-steps
#define NCF 8          // 8 col-frags of 16 (cols 0..99 = h, 100 = logit, 101..127 = 0)
#define BM 16          // rows per block tile
#define NIT 12         // 768 / 64 outer iters (BK = 64)

typedef __attribute__((ext_vector_type(8))) short short8;
typedef __attribute__((ext_vector_type(4))) float floatx4;

union U4S8 { uint4 v; short8 s8; unsigned u[4]; unsigned short us[8]; };

__device__ inline unsigned short f2bf(float f) {
    unsigned u = __float_as_uint(f);
    return (unsigned short)((u + 0x7fffu + ((u >> 16) & 1u)) >> 16);
}

// truncate-split of a float pair into packed bf16x2 hi / lo-residual.
__device__ inline void split2(float x0, float x1, unsigned& hi, unsigned& lo) {
    unsigned u0 = __float_as_uint(x0), u1 = __float_as_uint(x1);
    unsigned h0 = u0 & 0xFFFF0000u, h1 = u1 & 0xFFFF0000u;
    hi = (u0 >> 16) | h1;
    float r0 = x0 - __uint_as_float(h0);
    float r1 = x1 - __uint_as_float(h1);
    lo = (__float_as_uint(r0) >> 16) | (__float_as_uint(r1) & 0xFFFF0000u);
}

// Kernel 0: pack B = [ffnn_w | att_w | 0] (768 x 128) into MFMA B-frag order, bf16.
// Frag (ks, cf) at (ks*8+cf)*64: lane l holds B[ks*32 + (l>>4)*8 + j][cf*16 + (l&15)].
__global__ __launch_bounds__(256) void pack_b_kernel(
    const float* __restrict__ ffnn_w, const float* __restrict__ att_w,
    uint4* __restrict__ Bfrag)
{
    int ks = blockIdx.x;
    for (int idx = threadIdx.x; idx < NCF * 64; idx += 256) {
        int cf = idx >> 6, lane = idx & 63;
        int q = lane >> 4, r = lane & 15;
        int n = cf * 16 + r;
        U4S8 p;
#pragma unroll
        for (int j = 0; j < 8; j++) {
            int k = ks * 32 + q * 8 + j;
            float v = (n < NH) ? ffnn_w[(size_t)k * NH + n]
                               : (n == NH ? att_w[k] : 0.f);
            p.us[j] = f2bf(v);
        }
        Bfrag[(size_t)(ks * NCF + cf) * 64 + lane] = p.v;
    }
}

// Kernel 1: proj. 1024 blocks x 256 threads (16 waves/CU). Tile: 16 rows x 128
// cols; wave w owns col-frags {2w, 2w+1}. A is converted to bf16 hi/lo ONCE at
// staging time and stored in LDS (same 4 B/elem as fp32); MFMA loop reads
// b128 fragments directly — no per-wave conversion. B register-direct from L2
// with depth-1 prefetch.
__global__ __launch_bounds__(256, 4) void proj_kernel(
    const float* __restrict__ seq, const uint4* __restrict__ Bfrag,
    float* __restrict__ P, float* __restrict__ Lg)
{
    __shared__ unsigned Ahi[BM][36];   // bf16-hi pairs; row stride 144 B
    __shared__ unsigned Alo[BM][36];   // bf16-lo pairs
    const int t = threadIdx.x;
    const int wave = t >> 6, lane = t & 63;
    const int q = lane >> 4, r = lane & 15;
    const int cf0 = wave * 2;
    const int row0 = blockIdx.x * BM;

    floatx4 acc[2] = {{0.f,0.f,0.f,0.f},{0.f,0.f,0.f,0.f}};

    // staging: thread t owns float4 (row sr, k-quad sc) — fully coalesced
    const int sr = t >> 4, sc = t & 15;
    const float4* gA = (const float4*)(seq + (size_t)(row0 + sr) * ND);
    float4 sv = gA[sc];

    const uint4* bp = Bfrag + (size_t)cf0 * 64 + lane;
    // iter i, local k-step ksl: frag offset i*1024 + ksl*512 + {0,64}
    uint4 Bc0 = bp[0], Bc1 = bp[64], Bc2 = bp[512], Bc3 = bp[512 + 64];

    for (int i = 0; i < NIT; ++i) {
        unsigned h01, l01, h23, l23;
        split2(sv.x, sv.y, h01, l01);
        split2(sv.z, sv.w, h23, l23);
        __syncthreads();                     // prior iter's LDS reads done
        { uint2 u; u.x = h01; u.y = h23; *(uint2*)&Ahi[sr][sc * 2] = u; }
        { uint2 u; u.x = l01; u.y = l23; *(uint2*)&Alo[sr][sc * 2] = u; }
        __syncthreads();                     // tile i visible

        const int ni = (i + 1 < NIT) ? i + 1 : i;
        sv = gA[ni * 16 + sc];               // prefetch A tile i+1
        const size_t nb = (size_t)ni * 1024;
        uint4 Bn0 = bp[nb], Bn1 = bp[nb + 64], Bn2 = bp[nb + 512], Bn3 = bp[nb + 512 + 64];

#pragma unroll
        for (int ksl = 0; ksl < 2; ++ksl) {
            U4S8 ah, al, b0, b1;
            ah.v = *(const uint4*)&Ahi[r][ksl * 16 + q * 4];
            al.v = *(const uint4*)&Alo[r][ksl * 16 + q * 4];
            b0.v = ksl ? Bc2 : Bc0;
            b1.v = ksl ? Bc3 : Bc1;
            acc[0] = __builtin_amdgcn_mfma_f32_16x16x32_bf16(ah.s8, b0.s8, acc[0], 0, 0, 0);
            acc[0] = __builtin_amdgcn_mfma_f32_16x16x32_bf16(al.s8, b0.s8, acc[0], 0, 0, 0);
            acc[1] = __builtin_amdgcn_mfma_f32_16x16x32_bf16(ah.s8, b1.s8, acc[1], 0, 0, 0);
            acc[1] = __builtin_amdgcn_mfma_f32_16x16x32_bf16(al.s8, b1.s8, acc[1], 0, 0, 0);
        }
        Bc0 = Bn0; Bc1 = Bn1; Bc2 = Bn2; Bc3 = Bn3;
    }

    // C/D layout: col = (cf0+c)*16 + r, row = row0 + q*4 + reg
#pragma unroll
    for (int c = 0; c < 2; ++c) {
        const int col = (cf0 + c) * 16 + r;
        const int rowb = row0 + q * 4;
        if (col < NH) {
#pragma unroll
            for (int reg = 0; reg < 4; ++reg)
                P[(size_t)(rowb + reg) * LDP + col] = acc[c][reg];
        } else if (col == NH) {
#pragma unroll
            for (int reg = 0; reg < 4; ++reg)
                Lg[rowb + reg] = acc[c][reg];
        }
    }
}

// Kernel 2: TWO spans per wave (half-wave each, width-32 shuffles) -> 2x
// independent load streams per wave. Loads predicated on i<w (half-uniform
// exec mask): no fetch for dead widths, still fully unrolled/independent.
__global__ __launch_bounds__(256, 4) void span_kernel(
    const int* __restrict__ span_idx, const int* __restrict__ span_mask,
    const float* __restrict__ P, const float* __restrict__ Lg,
    const float* __restrict__ ffnn_b, float* __restrict__ out)
{
    const int hw = threadIdx.x >> 5, lane = threadIdx.x & 31;
    const int gs = blockIdx.x * 8 + hw;            // [0, 4096)
    const int b = gs / NSP;
    const int st = span_idx[2 * gs];
    int w = span_idx[2 * gs + 1] - st;             // width in [1, MAXW]
    w = max(1, min(w, MAXW));

    float lg = (lane < w) ? Lg[b * NS + st + lane] : -1e30f;
    float mx = lg;
#pragma unroll
    for (int off = 16; off > 0; off >>= 1) mx = fmaxf(mx, __shfl_xor(mx, off, 32));
    float e = (lane < w) ? __expf(lg - mx) : 0.f;
    float sum = e;
#pragma unroll
    for (int off = 16; off > 0; off >>= 1) sum += __shfl_xor(sum, off, 32);
    float attn = e / sum;                          // 0 for lanes >= w

    int cl = min(lane, 24);
    const float4* Pb4 = (const float4*)(P + ((size_t)b * NS + st) * LDP) + cl;
    float4 acc = {0.f, 0.f, 0.f, 0.f};
#pragma unroll
    for (int i = 0; i < MAXW; ++i) {
        float a = __shfl(attn, i, 32);
        if (i < w) {                               // half-uniform predicate
            float4 v = Pb4[i * (LDP / 4)];
            acc.x += a * v.x; acc.y += a * v.y; acc.z += a * v.z; acc.w += a * v.w;
        }
    }

    if (lane < 25) {
        float m = (float)span_mask[gs];
        float4 bias = ((const float4*)ffnn_b)[lane];
        float4 o;
        o.x = tanhf(m * acc.x + bias.x);
        o.y = tanhf(m * acc.y + bias.y);
        o.z = tanhf(m * acc.z + bias.z);
        o.w = tanhf(m * acc.w + bias.w);
        *(float4*)(out + (size_t)gs * NH + 4 * lane) = o;
    }
}

extern "C" void kernel_launch(void* const* d_in, const int* in_sizes, int n_in,
                              void* d_out, int out_size, void* d_ws, size_t ws_size,
                              hipStream_t stream) {
    const float* seq      = (const float*)d_in[0];  // [B,S,D]
    const int*   span_idx = (const int*)d_in[1];    // [B,N,2] int32 on device
    const int*   span_msk = (const int*)d_in[2];    // [B,N]
    const float* att_w    = (const float*)d_in[3];  // [D,1]
    // d_in[4] = att_b: cancels inside softmax — unused
    const float* ffnn_w   = (const float*)d_in[5];  // [D,H]
    const float* ffnn_b   = (const float*)d_in[6];  // [H]
    float* out = (float*)d_out;                     // [B,N,H]

    char* ws = (char*)d_ws;
    size_t off = 0;
    float* P     = (float*)(ws + off); off += (size_t)NB * NS * LDP * 4;    // 6.82 MB
    uint4* Bfrag = (uint4*)(ws + off); off += (size_t)NKS * NCF * 64 * 16;  // 192 KB
    float* Lg    = (float*)(ws + off);                                      // 64 KB

    pack_b_kernel<<<NKS, 256, 0, stream>>>(ffnn_w, att_w, Bfrag);
    proj_kernel<<<(NB * NS) / BM, 256, 0, stream>>>(seq, Bfrag, P, Lg);
    span_kernel<<<(NB * NSP) / 8, 256, 0, stream>>>(span_idx, span_msk, P, Lg, ffnn_b, out);
}